// Round 3
// baseline (75.821 us; speedup 1.0000x reference)
//
#include <hip/hip_runtime.h>

typedef float v2f __attribute__((ext_vector_type(2)));

#if defined(__has_builtin) && __has_builtin(__builtin_amdgcn_exp2f)
#  define FAST_EXP2(x) __builtin_amdgcn_exp2f(x)
#else
#  define FAST_EXP2(x) exp2f(x)
#endif
#if defined(__has_builtin) && __has_builtin(__builtin_amdgcn_rsqf)
#  define FAST_RSQ(x) __builtin_amdgcn_rsqf(x)
#else
#  define FAST_RSQ(x) rsqrtf(x)
#endif

// Pack (2,512,6) vortex features into (2,512) float4 {y, x, tau, -log2e/sig^2}
// in d_ws so the main kernel's inner loop reads them via SCALAR loads.
__global__ __launch_bounds__(256)
void GaussianFalloff_prep(const float* __restrict__ vortex,
                          float4* __restrict__ sv) {
    const int i = blockIdx.x * 256 + threadIdx.x;   // 0..1023 = b*512 + v
    const float* __restrict__ p = vortex + (size_t)i * 6;
    const float sig = p[3];
    sv[i] = make_float4(p[0], p[1], p[2], -1.4426950408889634f / (sig * sig));
}

// out[b,p,0] =  sum_v tau_v * exp(-r2/sig^2) * rsqrt(r2) * (p1 - x_v)
// out[b,p,1] = -sum_v tau_v * exp(-r2/sig^2) * rsqrt(r2) * (p0 - y_v)
//
// Split-K x4 (one wave per vortex-quarter), 2 points/thread packed as v2f
// (v_pk_*_f32), vortex constants loop-uniform -> s_load_dwordx4 from K$.
__global__ __launch_bounds__(256, 4)
void GaussianFalloffKernel_83434034692733_kernel(
    const float4* __restrict__ sv,      // (2, 512) packed, in d_ws
    const float* __restrict__ points,   // (2, 65536, 2)
    float* __restrict__ out)            // (2, 65536, 2)
{
    constexpr int NQ  = 4;                 // split-K quarters (= waves/block)
    constexpr int VQ  = 512 / NQ;          // 128 vortices per quarter
    constexpr int PTS = 128;               // points per block (64 lanes x 2)
    constexpr int BPB = 65536 / PTS;       // 512 blocks per batch

    __shared__ v2f red[NQ][PTS];           // 4 KB cross-wave partials

    const int b    = blockIdx.x / BPB;
    const int base = (blockIdx.x % BPB) * PTS;
    const int tid  = threadIdx.x;
    const int q    = tid >> 6;             // wave index == vortex quarter
    const int h    = tid & 63;             // lane

    const float2* __restrict__ pp =
        (const float2*)points + (size_t)b * 65536 + base;
    const float2 pA = pp[h];
    const float2 pB = pp[h + 64];
    const v2f py = { pA.x, pB.x };
    const v2f px = { pA.y, pB.y };

    v2f acc0 = { 0.0f, 0.0f };
    v2f acc1 = { 0.0f, 0.0f };

    const float4* __restrict__ svq = sv + b * 512 + q * VQ;
    #pragma unroll 8
    for (int v = 0; v < VQ; ++v) {
        const float4 s = svq[v];            // uniform -> s_load (scalar cache)
        const v2f dy = py - s.x;            // p0 - y_v  (both points)
        const v2f dx = px - s.y;            // p1 - x_v
        const v2f r2 = dy * dy + dx * dx;   // v_pk_mul + v_pk_fma
        v2f e, ri;
        e.x  = FAST_EXP2(r2.x * s.w);       // exp(-r2/sig^2)
        e.y  = FAST_EXP2(r2.y * s.w);
        ri.x = FAST_RSQ(r2.x);              // 1/sqrt(r2)
        ri.y = FAST_RSQ(r2.y);
        const v2f f = (e * ri) * s.z;
        acc0 += f * dx;
        acc1 -= f * dy;
    }

    red[q][h]      = (v2f){ acc0.x, acc1.x };   // point base+h
    red[q][h + 64] = (v2f){ acc0.y, acc1.y };   // point base+h+64
    __syncthreads();

    if (tid < PTS) {
        const v2f r = red[0][tid] + red[1][tid] + red[2][tid] + red[3][tid];
        ((float2*)out)[(size_t)b * 65536 + base + tid] = make_float2(r.x, r.y);
    }
}

extern "C" void kernel_launch(void* const* d_in, const int* in_sizes, int n_in,
                              void* d_out, int out_size, void* d_ws, size_t ws_size,
                              hipStream_t stream) {
    const float* vortex = (const float*)d_in[0];  // (2, 512, 6)
    const float* points = (const float*)d_in[1];  // (2, 256, 256, 2)
    float* out = (float*)d_out;                   // (2, 256, 256, 2)
    float4* sv = (float4*)d_ws;                   // 16 KB packed vortex data

    GaussianFalloff_prep<<<4, 256, 0, stream>>>(vortex, sv);

    const int blocks = 2 * (65536 / 128);  // 1024
    GaussianFalloffKernel_83434034692733_kernel<<<blocks, 256, 0, stream>>>(
        sv, points, out);
}

// Round 4
// 75.253 us; speedup vs baseline: 1.0076x; 1.0076x over previous
//
#include <hip/hip_runtime.h>

typedef float v2f __attribute__((ext_vector_type(2)));

#if defined(__has_builtin) && __has_builtin(__builtin_amdgcn_exp2f)
#  define FAST_EXP2(x) __builtin_amdgcn_exp2f(x)
#else
#  define FAST_EXP2(x) exp2f(x)
#endif
#if defined(__has_builtin) && __has_builtin(__builtin_amdgcn_rsqf)
#  define FAST_RSQ(x) __builtin_amdgcn_rsqf(x)
#else
#  define FAST_RSQ(x) rsqrtf(x)
#endif

// Pack (2,512,6) vortex features into (2,512) float4 {y, x, tau, -log2e/sig^2}
// in d_ws.
__global__ __launch_bounds__(256)
void GaussianFalloff_prep(const float* __restrict__ vortex,
                          float4* __restrict__ sv) {
    const int i = blockIdx.x * 256 + threadIdx.x;   // 0..1023 = b*512 + v
    const float* __restrict__ p = vortex + (size_t)i * 6;
    const float sig = p[3];
    sv[i] = make_float4(p[0], p[1], p[2], -1.4426950408889634f / (sig * sig));
}

// out[b,p,0] =  sum_v tau_v * exp(-r2/sig^2) * rsqrt(r2) * (p1 - x_v)
// out[b,p,1] = -sum_v tau_v * exp(-r2/sig^2) * rsqrt(r2) * (p0 - y_v)
//
// Split-K x8: 512-thread blocks (8 waves), wave q handles vortices
// [64q, 64q+64) for this block's 128 points (2/thread, packed v2f so
// non-trans math is v_pk_*_f32). 1024 blocks x 8 waves = 8192 waves =
// 8 waves/SIMD for latency hiding; __launch_bounds__(512,8) caps VGPR<=64.
__global__ __launch_bounds__(512, 8)
void GaussianFalloffKernel_83434034692733_kernel(
    const float4* __restrict__ sv,      // (2, 512) packed, in d_ws
    const float* __restrict__ points,   // (2, 65536, 2)
    float* __restrict__ out)            // (2, 65536, 2)
{
    constexpr int NQ  = 8;                 // split-K pieces (= waves/block)
    constexpr int VQ  = 512 / NQ;          // 64 vortices per wave
    constexpr int PTS = 128;               // points per block (64 lanes x 2)
    constexpr int BPB = 65536 / PTS;       // 512 blocks per batch

    __shared__ v2f red[NQ][PTS];           // 8 KB cross-wave partials

    const int b    = blockIdx.x / BPB;
    const int base = (blockIdx.x % BPB) * PTS;
    const int tid  = threadIdx.x;
    const int q    = tid >> 6;             // wave index == vortex slice
    const int h    = tid & 63;             // lane

    const float2* __restrict__ pp =
        (const float2*)points + (size_t)b * 65536 + base;
    const float2 pA = pp[h];
    const float2 pB = pp[h + 64];
    const v2f py = { pA.x, pB.x };
    const v2f px = { pA.y, pB.y };

    v2f acc0 = { 0.0f, 0.0f };
    v2f acc1 = { 0.0f, 0.0f };

    const float4* __restrict__ svq = sv + b * 512 + q * VQ;
    #pragma unroll 4
    for (int v = 0; v < VQ; ++v) {
        const float4 s = svq[v];            // wave-uniform (L1-hot)
        const v2f dy = py - s.x;            // p0 - y_v  (both points)
        const v2f dx = px - s.y;            // p1 - x_v
        const v2f r2 = dy * dy + dx * dx;   // v_pk_mul + v_pk_fma
        v2f e, ri;
        e.x  = FAST_EXP2(r2.x * s.w);       // exp(-r2/sig^2)
        e.y  = FAST_EXP2(r2.y * s.w);
        ri.x = FAST_RSQ(r2.x);              // 1/sqrt(r2)
        ri.y = FAST_RSQ(r2.y);
        const v2f f = (e * ri) * s.z;
        acc0 += f * dx;
        acc1 -= f * dy;
    }

    red[q][h]      = (v2f){ acc0.x, acc1.x };   // point base+h
    red[q][h + 64] = (v2f){ acc0.y, acc1.y };   // point base+h+64
    __syncthreads();

    if (tid < PTS) {
        v2f r = red[0][tid];
        #pragma unroll
        for (int i = 1; i < NQ; ++i) r += red[i][tid];
        ((float2*)out)[(size_t)b * 65536 + base + tid] = make_float2(r.x, r.y);
    }
}

extern "C" void kernel_launch(void* const* d_in, const int* in_sizes, int n_in,
                              void* d_out, int out_size, void* d_ws, size_t ws_size,
                              hipStream_t stream) {
    const float* vortex = (const float*)d_in[0];  // (2, 512, 6)
    const float* points = (const float*)d_in[1];  // (2, 256, 256, 2)
    float* out = (float*)d_out;                   // (2, 256, 256, 2)
    float4* sv = (float4*)d_ws;                   // 16 KB packed vortex data

    GaussianFalloff_prep<<<4, 256, 0, stream>>>(vortex, sv);

    const int blocks = 2 * (65536 / 128);  // 1024 blocks x 512 threads
    GaussianFalloffKernel_83434034692733_kernel<<<blocks, 512, 0, stream>>>(
        sv, points, out);
}

// Round 5
// 72.221 us; speedup vs baseline: 1.0499x; 1.0420x over previous
//
#include <hip/hip_runtime.h>

typedef float v2f __attribute__((ext_vector_type(2)));

#if defined(__has_builtin) && __has_builtin(__builtin_amdgcn_exp2f)
#  define FAST_EXP2(x) __builtin_amdgcn_exp2f(x)
#else
#  define FAST_EXP2(x) exp2f(x)
#endif
#if defined(__has_builtin) && __has_builtin(__builtin_amdgcn_rsqf)
#  define FAST_RSQ(x) __builtin_amdgcn_rsqf(x)
#else
#  define FAST_RSQ(x) rsqrtf(x)
#endif

// out[b,p,0] =  sum_v tau_v * exp(-r2/sig^2) * rsqrt(r2) * (p1 - x_v)
// out[b,p,1] = -sum_v tau_v * exp(-r2/sig^2) * rsqrt(r2) * (p0 - y_v)
//
// Coordinate pre-scaling: with a = sqrt(log2e)/|sig|, define
//   dy' = a*(p0-y), dx' = a*(p1-x), r2' = dy'^2+dx'^2 = (log2e/sig^2)*r2.
// Then exp(-r2/sig^2)*rsqrt(r2)*dx = exp2(-r2')*rsqrt(r2')*dx'  (the a
// factors cancel), so the inner loop needs no separate k*r2 multiply and
// the exp negation is a free source modifier.
//
// Single kernel (no prep launch): stage {a, -a*y, -a*x, tau} in LDS.
// Split-K x8: 512-thread blocks, wave q handles vortices [64q,64q+64) for
// the block's 128 points (2/thread, packed v2f -> v_pk_*_f32).
// 1024 blocks x 8 waves = 8 waves/SIMD.
__global__ __launch_bounds__(512, 8)
void GaussianFalloffKernel_83434034692733_kernel(
    const float* __restrict__ vortex,   // (2, 512, 6)
    const float* __restrict__ points,   // (2, 65536, 2)
    float* __restrict__ out)            // (2, 65536, 2)
{
    constexpr int NV  = 512;
    constexpr int NQ  = 8;                 // split-K pieces (= waves/block)
    constexpr int VQ  = NV / NQ;           // 64 vortices per wave
    constexpr int PTS = 128;               // points per block (64 lanes x 2)
    constexpr int BPB = 65536 / PTS;       // 512 blocks per batch

    __shared__ float4 sv[NV];              // {a, -a*y, -a*x, tau}, 8 KB
    __shared__ v2f    red[NQ][PTS];        // 8 KB cross-wave partials

    const int b    = blockIdx.x / BPB;
    const int base = (blockIdx.x % BPB) * PTS;
    const int tid  = threadIdx.x;
    const int q    = tid >> 6;             // wave index == vortex slice
    const int h    = tid & 63;             // lane

    // Stage: one vortex per thread (512 threads, 512 vortices).
    {
        const float* __restrict__ p = vortex + ((size_t)b * NV + tid) * 6;
        const float y   = p[0];
        const float x   = p[1];
        const float tau = p[2];
        const float sig = p[3];
        const float a   = 1.2011224087864498f / fabsf(sig);  // sqrt(log2e)/|sig|
        sv[tid] = make_float4(a, -a * y, -a * x, tau);
    }
    __syncthreads();

    // Two points per thread: base+h and base+h+64, packed SoA.
    const float2* __restrict__ pp =
        (const float2*)points + (size_t)b * 65536 + base;
    const float2 pA = pp[h];
    const float2 pB = pp[h + 64];
    const v2f py = { pA.x, pB.x };
    const v2f px = { pA.y, pB.y };

    v2f acc0 = { 0.0f, 0.0f };
    v2f acc1 = { 0.0f, 0.0f };

    const float4* __restrict__ svq = sv + q * VQ;
    #pragma unroll 4
    for (int v = 0; v < VQ; ++v) {
        const float4 s = svq[v];            // wave-uniform LDS broadcast
        const v2f dy = py * s.x + s.y;      // a*(p0 - y_v)   (pk_fma)
        const v2f dx = px * s.x + s.z;      // a*(p1 - x_v)   (pk_fma)
        const v2f r2 = dy * dy + dx * dx;   // pk_mul + pk_fma
        v2f e, ri;
        e.x  = FAST_EXP2(-r2.x);            // neg is a free src modifier
        e.y  = FAST_EXP2(-r2.y);
        ri.x = FAST_RSQ(r2.x);
        ri.y = FAST_RSQ(r2.y);
        const v2f f = (e * ri) * s.w;       // tau * exp * rsqrt (scaled)
        acc0 += f * dx;                     // pk_fma
        acc1 -= f * dy;                     // pk_fma (neg modifier)
    }

    red[q][h]      = (v2f){ acc0.x, acc1.x };   // point base+h
    red[q][h + 64] = (v2f){ acc0.y, acc1.y };   // point base+h+64
    __syncthreads();

    if (tid < PTS) {
        v2f r = red[0][tid];
        #pragma unroll
        for (int i = 1; i < NQ; ++i) r += red[i][tid];
        ((float2*)out)[(size_t)b * 65536 + base + tid] = make_float2(r.x, r.y);
    }
}

extern "C" void kernel_launch(void* const* d_in, const int* in_sizes, int n_in,
                              void* d_out, int out_size, void* d_ws, size_t ws_size,
                              hipStream_t stream) {
    const float* vortex = (const float*)d_in[0];  // (2, 512, 6)
    const float* points = (const float*)d_in[1];  // (2, 256, 256, 2)
    float* out = (float*)d_out;                   // (2, 256, 256, 2)

    const int blocks = 2 * (65536 / 128);  // 1024 blocks x 512 threads
    GaussianFalloffKernel_83434034692733_kernel<<<blocks, 512, 0, stream>>>(
        vortex, points, out);
}

// Round 6
// 71.840 us; speedup vs baseline: 1.0554x; 1.0053x over previous
//
#include <hip/hip_runtime.h>

typedef float v2f __attribute__((ext_vector_type(2)));

#if defined(__has_builtin) && __has_builtin(__builtin_amdgcn_exp2f)
#  define FAST_EXP2(x) __builtin_amdgcn_exp2f(x)
#else
#  define FAST_EXP2(x) exp2f(x)
#endif
#if defined(__has_builtin) && __has_builtin(__builtin_amdgcn_rsqf)
#  define FAST_RSQ(x) __builtin_amdgcn_rsqf(x)
#else
#  define FAST_RSQ(x) rsqrtf(x)
#endif

// out[b,p,0] =  sum_v tau_v * exp(-r2/sig^2) * rsqrt(r2) * (p1 - x_v)
// out[b,p,1] = -sum_v tau_v * exp(-r2/sig^2) * rsqrt(r2) * (p0 - y_v)
//
// Coordinate pre-scaling (a = sqrt(log2e)/|sig|): dy' = a*(p0-y),
// dx' = a*(p1-x), r2' = dy'^2+dx'^2 -> exp(-r2/sig^2)*rsqrt(r2)*dx =
// exp2(-r2')*rsqrt(r2')*dx' (a cancels); exp negation via src modifier.
//
// 4 points/thread (two v2f groups -> v_pk_*_f32) so each ds_read_b128
// broadcast serves 4 points: LDS pipe ~5 us < trans-pipe floor 6.8 us.
// Split-K x8: 512 blocks x 512 threads; wave q covers vortices [64q,64q+64)
// for the block's 256 points. 4096 waves = 4 waves/SIMD (occupancy proven
// non-binding in R4).
__global__ __launch_bounds__(512, 4)
void GaussianFalloffKernel_83434034692733_kernel(
    const float* __restrict__ vortex,   // (2, 512, 6)
    const float* __restrict__ points,   // (2, 65536, 2)
    float* __restrict__ out)            // (2, 65536, 2)
{
    constexpr int NV  = 512;
    constexpr int NQ  = 8;                 // split-K pieces (= waves/block)
    constexpr int VQ  = NV / NQ;           // 64 vortices per wave
    constexpr int PTS = 256;               // points per block (64 lanes x 4)
    constexpr int BPB = 65536 / PTS;       // 256 blocks per batch

    __shared__ float4 sv[NV];              // {a, -a*y, -a*x, tau}, 8 KB
    __shared__ v2f    red[NQ][PTS];        // 16 KB cross-wave partials

    const int b    = blockIdx.x / BPB;
    const int base = (blockIdx.x % BPB) * PTS;
    const int tid  = threadIdx.x;
    const int q    = tid >> 6;             // wave index == vortex slice
    const int h    = tid & 63;             // lane

    // Stage: one vortex per thread (512 threads, 512 vortices).
    {
        const float* __restrict__ p = vortex + ((size_t)b * NV + tid) * 6;
        const float y   = p[0];
        const float x   = p[1];
        const float tau = p[2];
        const float sig = p[3];
        const float a   = 1.2011224087864498f / fabsf(sig);  // sqrt(log2e)/|sig|
        sv[tid] = make_float4(a, -a * y, -a * x, tau);
    }
    __syncthreads();

    // Four points per thread: base + h + {0,64,128,192}, packed SoA.
    const float2* __restrict__ pp =
        (const float2*)points + (size_t)b * 65536 + base;
    const float2 p0 = pp[h];
    const float2 p1 = pp[h + 64];
    const float2 p2 = pp[h + 128];
    const float2 p3 = pp[h + 192];
    const v2f pyA = { p0.x, p1.x }, pxA = { p0.y, p1.y };
    const v2f pyB = { p2.x, p3.x }, pxB = { p2.y, p3.y };

    v2f acc0A = { 0.0f, 0.0f }, acc1A = { 0.0f, 0.0f };
    v2f acc0B = { 0.0f, 0.0f }, acc1B = { 0.0f, 0.0f };

    const float4* __restrict__ svq = sv + q * VQ;
    #pragma unroll 4
    for (int v = 0; v < VQ; ++v) {
        const float4 s = svq[v];              // wave-uniform LDS broadcast
        const v2f dyA = pyA * s.x + s.y;      // a*(p0 - y_v)   (pk_fma)
        const v2f dxA = pxA * s.x + s.z;      // a*(p1 - x_v)
        const v2f dyB = pyB * s.x + s.y;
        const v2f dxB = pxB * s.x + s.z;
        const v2f r2A = dyA * dyA + dxA * dxA;
        const v2f r2B = dyB * dyB + dxB * dxB;
        v2f eA, eB, riA, riB;
        eA.x  = FAST_EXP2(-r2A.x);  eA.y  = FAST_EXP2(-r2A.y);
        eB.x  = FAST_EXP2(-r2B.x);  eB.y  = FAST_EXP2(-r2B.y);
        riA.x = FAST_RSQ(r2A.x);    riA.y = FAST_RSQ(r2A.y);
        riB.x = FAST_RSQ(r2B.x);    riB.y = FAST_RSQ(r2B.y);
        const v2f fA = (eA * riA) * s.w;      // tau * exp * rsqrt (scaled)
        const v2f fB = (eB * riB) * s.w;
        acc0A += fA * dxA;
        acc1A -= fA * dyA;
        acc0B += fB * dxB;
        acc1B -= fB * dyB;
    }

    red[q][h]       = (v2f){ acc0A.x, acc1A.x };
    red[q][h + 64]  = (v2f){ acc0A.y, acc1A.y };
    red[q][h + 128] = (v2f){ acc0B.x, acc1B.x };
    red[q][h + 192] = (v2f){ acc0B.y, acc1B.y };
    __syncthreads();

    // 512 threads reduce 256 points: thread t handles point t/2's component t&1.
    if (tid < 2 * PTS) {
        const int pt = tid >> 1;
        const int c  = tid & 1;
        float r = red[0][pt][c];
        #pragma unroll
        for (int i = 1; i < NQ; ++i) r += red[i][pt][c];
        out[((size_t)b * 65536 + base + pt) * 2 + c] = r;
    }
}

extern "C" void kernel_launch(void* const* d_in, const int* in_sizes, int n_in,
                              void* d_out, int out_size, void* d_ws, size_t ws_size,
                              hipStream_t stream) {
    const float* vortex = (const float*)d_in[0];  // (2, 512, 6)
    const float* points = (const float*)d_in[1];  // (2, 256, 256, 2)
    float* out = (float*)d_out;                   // (2, 256, 256, 2)

    const int blocks = 2 * (65536 / 256);  // 512 blocks x 512 threads
    GaussianFalloffKernel_83434034692733_kernel<<<blocks, 512, 0, stream>>>(
        vortex, points, out);
}